// Round 1
// baseline (98.484 us; speedup 1.0000x reference)
//
#include <hip/hip_runtime.h>
#include <hip/hip_bf16.h>
#include <cstdint>

#define NROWS 8192
#define NPER  4096
#define DIM   512
#define TEMP_INV 10.0f
#define NB2 32          // 8192 / 256 row-blocks
#define NBLK 528        // NB2*(NB2+1)/2

typedef __bf16 bf16x8 __attribute__((ext_vector_type(8)));
typedef float  f32x4  __attribute__((ext_vector_type(4)));

__device__ __forceinline__ unsigned short f2bf(float f) {
  unsigned int u = __builtin_bit_cast(unsigned int, f);
  u += 0x7FFFu + ((u >> 16) & 1u);
  return (unsigned short)(u >> 16);
}
__device__ __forceinline__ float bf2f(unsigned short h) {
  unsigned int u = ((unsigned int)h) << 16;
  return __builtin_bit_cast(float, u);
}

// ---------------------------------------------------------------------------
// Kernel 1: L2-normalize rows of [view0; view1] -> z (bf16, [8192][512]).
// Also zeroes rowsum (replaces hipMemsetAsync dispatch).
// ---------------------------------------------------------------------------
__global__ __launch_bounds__(256) void k_normalize(const float* __restrict__ v0,
                                                   const float* __restrict__ v1,
                                                   unsigned short* __restrict__ z,
                                                   float* __restrict__ rowsum) {
  if (blockIdx.x < 32) rowsum[blockIdx.x * 256 + threadIdx.x] = 0.f;
  const int wid  = (blockIdx.x * 256 + threadIdx.x) >> 6;  // row
  const int lane = threadIdx.x & 63;
  if (wid >= NROWS) return;
  const float* src = (wid < NPER) ? (v0 + (size_t)wid * DIM)
                                  : (v1 + (size_t)(wid - NPER) * DIM);
  float4 a = *(const float4*)(src + lane * 8);
  float4 b = *(const float4*)(src + lane * 8 + 4);
  float ss = a.x*a.x + a.y*a.y + a.z*a.z + a.w*a.w
           + b.x*b.x + b.y*b.y + b.z*b.z + b.w*b.w;
  #pragma unroll
  for (int m = 1; m < 64; m <<= 1) ss += __shfl_xor(ss, m);
  float inv = 1.0f / fmaxf(sqrtf(ss), 1e-12f);
  union { unsigned short us[8]; uint4 v; } p;
  p.us[0] = f2bf(a.x * inv); p.us[1] = f2bf(a.y * inv);
  p.us[2] = f2bf(a.z * inv); p.us[3] = f2bf(a.w * inv);
  p.us[4] = f2bf(b.x * inv); p.us[5] = f2bf(b.y * inv);
  p.us[6] = f2bf(b.z * inv); p.us[7] = f2bf(b.w * inv);
  *(uint4*)(z + (size_t)wid * DIM + lane * 8) = p.v;
}

// ---------------------------------------------------------------------------
// Kernel 2: symmetric fused G = z z^T, 256x256 upper-triangular blocks,
// 8 waves (2x4), BK=64 double-buffered.
// NEW: m201-style 4-sub-phase interleave per K-step (T3), counted vmcnt at
// iteration head only (T4, never 0 until last step), s_setprio around each
// 16-MFMA cluster (T5). T2 XOR-swizzled LDS + T1 chunked XCD swizzle kept.
// Positive-pair dots (s[i] = dot(z_i, z_{i+4096})) are harvested from the
// raw accumulators of the 16 tiles with bj == bi+16 (k_posdot eliminated).
//
// Phase schedule per K-step kt (slot cur = kt&1), per wave:
//   head: stage T_{kt+1} -> slot cur^1 (8 loads); s_waitcnt vmcnt(8); barrier
//         (T_kt certified landed for ALL waves; T_{kt+1} stays in flight)
//   4 phases (kk x row-half): [4-8 ds_read_b128] barrier; lgkmcnt(0);
//         setprio(1); 16 MFMA; setprio(0); barrier
// Slot-reuse safety: every wave drains its slot-cur reads (lgkmcnt(0))
// before its final phase barrier, and the overwriting stage is issued only
// after the next iteration head -> no LDS write-after-read race.
// ---------------------------------------------------------------------------
__global__ __launch_bounds__(512, 2) void k_gemm_sym(const unsigned short* __restrict__ z,
                                                     float* __restrict__ rowsum,
                                                     float* __restrict__ s) {
  __shared__ __align__(16) unsigned short As[2][256 * 64];
  __shared__ __align__(16) unsigned short Bs[2][256 * 64];
  __shared__ float racc[4][256];   // [wc][row-in-block] partial row sums
  __shared__ float cacc[2][256];   // [wr][col-in-block] partial col sums

  const int tid  = threadIdx.x;
  const int lane = tid & 63;
  const int w    = tid >> 6;      // 0..7
  const int wr   = w >> 2;        // 0..1 (row half)
  const int wc   = w & 3;         // 0..3 (col quarter)

  // T1: bijective chunked XCD swizzle (528 % 8 == 0)
  const int orig = blockIdx.x;
  const int t = (orig & 7) * (NBLK / 8) + (orig >> 3);
  // decode upper-triangular block (bi <= bj)
  int bi = (int)((65.0f - sqrtf((float)(4225 - 8 * t))) * 0.5f);
  while ((bi + 1) * NB2 - ((bi + 1) * bi) / 2 <= t) ++bi;
  while (bi * NB2 - (bi * (bi - 1)) / 2 > t) --bi;
  const int bj   = bi + (t - (bi * NB2 - (bi * (bi - 1)) / 2));
  const int brow = bi * 256;
  const int bcol = bj * 256;
  const bool diag   = (bi == bj);
  const bool pair16 = (bj - bi == 16);   // tile contains positive-pair diagonal

  f32x4 acc[8][4];
  const f32x4 zero = {0.f, 0.f, 0.f, 0.f};
  #pragma unroll
  for (int m = 0; m < 8; ++m)
    #pragma unroll
    for (int n = 0; n < 4; ++n) acc[m][n] = zero;

  // stage one BK=64 K-slab (A and B tiles, 32 KB each) into buffer buf.
  // 8 global_load_lds per thread. LDS dest linear; global source pre-swizzled
  // (rule #21) to realize phys_byte = logical_byte ^ ((row & 7) << 4).
  const int srow = (lane >> 3);                  // 0..7 row within chunk
  const int skof = 8 * ((lane & 7) ^ srow);      // pre-swizzled k-offset (elems)
  auto stage = [&](int buf, int k0) {
    #pragma unroll
    for (int i = 0; i < 4; ++i) {
      const int c = w * 4 + i;                   // chunk 0..31 (8 rows each)
      const int row_in = c * 8 + srow;
      const unsigned short* ga = z + (size_t)(brow + row_in) * DIM + k0 + skof;
      const unsigned short* gb = z + (size_t)(bcol + row_in) * DIM + k0 + skof;
      __builtin_amdgcn_global_load_lds(
          (const __attribute__((address_space(1))) void*)ga,
          (__attribute__((address_space(3))) void*)(&As[buf][c * 512]), 16, 0, 0);
      __builtin_amdgcn_global_load_lds(
          (const __attribute__((address_space(1))) void*)gb,
          (__attribute__((address_space(3))) void*)(&Bs[buf][c * 512]), 16, 0, 0);
    }
  };

  stage(0, 0);        // prologue: T0 in flight (8 loads)

  const int r0 = lane & 15;
  const int g  = lane >> 4;
  const int sw = (r0 & 7) << 4;                  // swizzle XOR (bits 4-6)

  for (int kt = 0; kt < 8; ++kt) {
    const int cur = kt & 1;
    // ---- iteration head: prefetch next slab, certify current one ----
    if (kt < 7) {
      stage(cur ^ 1, (kt + 1) * 64);             // T_{kt+1} -> other slot
      // in flight: T_kt (8, oldest) + T_{kt+1} (8). Wait T_kt only.
      asm volatile("s_waitcnt vmcnt(8)" ::: "memory");
    } else {
      asm volatile("s_waitcnt vmcnt(0)" ::: "memory");
    }
    __builtin_amdgcn_s_barrier();                // all waves: T_kt visible

    const char* Ab = (const char*)&As[cur][0];
    const char* Bb = (const char*)&Bs[cur][0];
    bf16x8 aq[4], bq[4];

    // ---- 4 sub-phases: (kk = K-half) x (mh = row-half of wave's 128) ----
    #pragma unroll
    for (int kk = 0; kk < 2; ++kk) {
      const int kb = kk * 64 + g * 16;           // k byte-offset within row
      #pragma unroll
      for (int mh = 0; mh < 2; ++mh) {
        if (mh == 0) {                           // B quad lives across both mh
          #pragma unroll
          for (int n = 0; n < 4; ++n)
            bq[n] = *(const bf16x8*)(Bb + (((wc * 64 + n * 16 + r0) * 128 + kb) ^ sw));
        }
        #pragma unroll
        for (int m = 0; m < 4; ++m)
          aq[m] = *(const bf16x8*)(Ab + (((wr * 128 + mh * 64 + m * 16 + r0) * 128 + kb) ^ sw));
        __builtin_amdgcn_s_barrier();            // reads in flight during wait
        asm volatile("s_waitcnt lgkmcnt(0)" ::: "memory");
        __builtin_amdgcn_s_setprio(1);
        #pragma unroll
        for (int m = 0; m < 4; ++m)
          #pragma unroll
          for (int n = 0; n < 4; ++n)
            acc[mh * 4 + m][n] = __builtin_amdgcn_mfma_f32_16x16x32_bf16(
                aq[m], bq[n], acc[mh * 4 + m][n], 0, 0, 0);
        __builtin_amdgcn_s_setprio(0);
        __builtin_amdgcn_s_barrier();            // phase lock
      }
    }
  }

  // ---- epilogue: exp(10*g); row sums + col sums (symmetry); pair dots ----
  float cs[4] = {0.f, 0.f, 0.f, 0.f};
  const int grow0 = brow + wr * 128;
  const int gcol0 = bcol + wc * 64;
  #pragma unroll
  for (int m = 0; m < 8; ++m) {
    #pragma unroll
    for (int j = 0; j < 4; ++j) {
      const int grow = grow0 + m * 16 + g * 4 + j;
      float v = 0.f;
      #pragma unroll
      for (int n = 0; n < 4; ++n) {
        const int gcol = gcol0 + n * 16 + r0;
        const float raw = acc[m][n][j];
        const float e = __expf(raw * TEMP_INV);
        if (grow != gcol) { v += e; cs[n] += e; }   // skip self-similarity
        if (pair16 && (grow + NPER == gcol)) {      // positive-pair raw dot
          s[grow] = raw;                            // dot(z_i, z_{i+NPER})
          s[gcol] = raw;                            // symmetric partner
        }
      }
      v += __shfl_xor(v, 1);
      v += __shfl_xor(v, 2);
      v += __shfl_xor(v, 4);
      v += __shfl_xor(v, 8);
      if (r0 == 0) racc[wc][wr * 128 + m * 16 + g * 4 + j] = v;
    }
  }
  #pragma unroll
  for (int n = 0; n < 4; ++n) {
    float v = cs[n];
    v += __shfl_xor(v, 16);
    v += __shfl_xor(v, 32);
    if (lane < 16) cacc[wr][wc * 64 + n * 16 + lane] = v;
  }
  __syncthreads();
  if (tid < 256) {
    atomicAdd(&rowsum[brow + tid],
              racc[0][tid] + racc[1][tid] + racc[2][tid] + racc[3][tid]);
  } else if (!diag) {
    const int i = tid - 256;
    atomicAdd(&rowsum[bcol + i], cacc[0][i] + cacc[1][i]);
  }
}

// ---------------------------------------------------------------------------
// Kernel 3: loss = mean_i( log(denom_i) - s_i/T )
// ---------------------------------------------------------------------------
__global__ __launch_bounds__(256) void k_loss(const float* __restrict__ rowsum,
                                              const float* __restrict__ s,
                                              float* __restrict__ out) {
  __shared__ float red[256];
  float acc = 0.f;
  for (int i = threadIdx.x; i < NROWS; i += 256)
    acc += logf(rowsum[i]) - s[i] * TEMP_INV;
  red[threadIdx.x] = acc;
  __syncthreads();
  for (int st = 128; st > 0; st >>= 1) {
    if (threadIdx.x < st) red[threadIdx.x] += red[threadIdx.x + st];
    __syncthreads();
  }
  if (threadIdx.x == 0) out[0] = red[0] / (float)NROWS;
}

extern "C" void kernel_launch(void* const* d_in, const int* in_sizes, int n_in,
                              void* d_out, int out_size, void* d_ws, size_t ws_size,
                              hipStream_t stream) {
  const float* v0 = (const float*)d_in[0];
  const float* v1 = (const float*)d_in[1];
  float* out = (float*)d_out;

  unsigned short* z = (unsigned short*)d_ws;                    // 8192*512*2 B
  float* rowsum = (float*)((char*)d_ws + (size_t)NROWS * DIM * 2);
  float* s      = rowsum + NROWS;

  k_normalize<<<NROWS / 4, 256, 0, stream>>>(v0, v1, z, rowsum);
  k_gemm_sym<<<NBLK, 512, 0, stream>>>(z, rowsum, s);
  k_loss<<<1, 256, 0, stream>>>(rowsum, s, out);
}

// Round 2
// 85.604 us; speedup vs baseline: 1.1505x; 1.1505x over previous
//
#include <hip/hip_runtime.h>
#include <hip/hip_bf16.h>
#include <cstdint>

#define NROWS 8192
#define NPER  4096
#define DIM   512
#define TEMP_INV 10.0f
#define NB    64        // 8192 / 128 row-blocks
#define NBLK  2080      // NB*(NB+1)/2 upper-tri 128x128 tiles
#define PAIR_OFF 32     // NPER / 128

typedef __bf16 bf16x8 __attribute__((ext_vector_type(8)));
typedef float  f32x4  __attribute__((ext_vector_type(4)));

__device__ __forceinline__ unsigned short f2bf(float f) {
  unsigned int u = __builtin_bit_cast(unsigned int, f);
  u += 0x7FFFu + ((u >> 16) & 1u);
  return (unsigned short)(u >> 16);
}

// ---------------------------------------------------------------------------
// Kernel 1: L2-normalize rows of [view0; view1] -> z (bf16, [8192][512]).
// Also zeroes rowsum (replaces hipMemsetAsync dispatch).
// ---------------------------------------------------------------------------
__global__ __launch_bounds__(256) void k_normalize(const float* __restrict__ v0,
                                                   const float* __restrict__ v1,
                                                   unsigned short* __restrict__ z,
                                                   float* __restrict__ rowsum) {
  if (blockIdx.x < 32) rowsum[blockIdx.x * 256 + threadIdx.x] = 0.f;
  const int wid  = (blockIdx.x * 256 + threadIdx.x) >> 6;  // row
  const int lane = threadIdx.x & 63;
  if (wid >= NROWS) return;
  const float* src = (wid < NPER) ? (v0 + (size_t)wid * DIM)
                                  : (v1 + (size_t)(wid - NPER) * DIM);
  float4 a = *(const float4*)(src + lane * 8);
  float4 b = *(const float4*)(src + lane * 8 + 4);
  float ss = a.x*a.x + a.y*a.y + a.z*a.z + a.w*a.w
           + b.x*b.x + b.y*b.y + b.z*b.z + b.w*b.w;
  #pragma unroll
  for (int m = 1; m < 64; m <<= 1) ss += __shfl_xor(ss, m);
  float inv = 1.0f / fmaxf(sqrtf(ss), 1e-12f);
  union { unsigned short us[8]; uint4 v; } p;
  p.us[0] = f2bf(a.x * inv); p.us[1] = f2bf(a.y * inv);
  p.us[2] = f2bf(a.z * inv); p.us[3] = f2bf(a.w * inv);
  p.us[4] = f2bf(b.x * inv); p.us[5] = f2bf(b.y * inv);
  p.us[6] = f2bf(b.z * inv); p.us[7] = f2bf(b.w * inv);
  *(uint4*)(z + (size_t)wid * DIM + lane * 8) = p.v;
}

// ---------------------------------------------------------------------------
// Kernel 2: symmetric fused G = z z^T, 128x128 upper-triangular tiles
// (2080 blocks -> tail inflation ~12% vs 45% at 256^2), 4 waves (2x2),
// per-wave 64x64 (acc[4][4] = 64 AGPR), BK=64 double-buffered,
// 2-phase loop with counted vmcnt (T4; proven round-0 structure),
// T2 XOR-swizzled LDS (linear dest + pre-swizzled global source, rule #21),
// T1 chunked XCD block swizzle (2080 = 8*260, bijective).
// LDS 66 KB -> 2 blocks/CU co-resident: cross-block TLP hides the
// vmcnt/barrier stalls (m114 mechanism) that 1-block/CU could not.
// Positive-pair dots harvested from raw acc of tiles with bj-bi == 32
// (no separate k_posdot kernel).
// ---------------------------------------------------------------------------
__global__ __launch_bounds__(256, 2) void k_gemm_sym(const unsigned short* __restrict__ z,
                                                     float* __restrict__ rowsum,
                                                     float* __restrict__ s) {
  __shared__ __align__(16) unsigned short As[2][128 * 64];
  __shared__ __align__(16) unsigned short Bs[2][128 * 64];
  __shared__ float racc[2][128];   // [wc][row-in-block] partial row sums
  __shared__ float cacc[2][128];   // [wr][col-in-block] partial col sums

  const int tid  = threadIdx.x;
  const int lane = tid & 63;
  const int w    = tid >> 6;      // 0..3
  const int wr   = w >> 1;        // 0..1 (row half)
  const int wc   = w & 1;         // 0..1 (col half)

  // T1: bijective chunked XCD swizzle (2080 % 8 == 0)
  const int orig = blockIdx.x;
  const int t = (orig & 7) * (NBLK / 8) + (orig >> 3);
  // decode upper-triangular block (bi <= bj): start(bi) = bi*NB - bi(bi-1)/2
  int bi = (int)((129.0f - sqrtf((float)(16641 - 8 * t))) * 0.5f);
  while ((bi + 1) * NB - ((bi + 1) * bi) / 2 <= t) ++bi;
  while (bi * NB - (bi * (bi - 1)) / 2 > t) --bi;
  const int bj   = bi + (t - (bi * NB - (bi * (bi - 1)) / 2));
  const int brow = bi * 128;
  const int bcol = bj * 128;
  const bool diag   = (bi == bj);
  const bool pair   = (bj - bi == PAIR_OFF);  // contains positive-pair diagonal

  f32x4 acc[4][4];
  const f32x4 zero = {0.f, 0.f, 0.f, 0.f};
  #pragma unroll
  for (int m = 0; m < 4; ++m)
    #pragma unroll
    for (int n = 0; n < 4; ++n) acc[m][n] = zero;

  // stage one BK=64 K-slab (A and B tiles, 16 KB each) into buffer buf.
  // 8 global_load_lds per thread (4 A + 4 B). LDS dest linear; global source
  // pre-swizzled (rule #21): phys_byte = logical_byte ^ ((row & 7) << 4).
  const int srow = (lane >> 3);                  // 0..7 row within chunk
  const int skof = 8 * ((lane & 7) ^ srow);      // pre-swizzled k-offset (elems)
  auto stage = [&](int buf, int k0) {
    #pragma unroll
    for (int i = 0; i < 4; ++i) {
      const int c = w * 4 + i;                   // chunk 0..15 (8 rows each)
      const int row_in = c * 8 + srow;
      const unsigned short* ga = z + (size_t)(brow + row_in) * DIM + k0 + skof;
      const unsigned short* gb = z + (size_t)(bcol + row_in) * DIM + k0 + skof;
      __builtin_amdgcn_global_load_lds(
          (const __attribute__((address_space(1))) void*)ga,
          (__attribute__((address_space(3))) void*)(&As[buf][c * 512]), 16, 0, 0);
      __builtin_amdgcn_global_load_lds(
          (const __attribute__((address_space(1))) void*)gb,
          (__attribute__((address_space(3))) void*)(&Bs[buf][c * 512]), 16, 0, 0);
    }
  };

  stage(0, 0);        // S(0): 8 loads/thread in flight
  stage(1, 64);       // S(1): 16 in flight

  const int r0 = lane & 15;
  const int g  = lane >> 4;
  const int sw = (r0 & 7) << 4;                  // swizzle XOR (bits 4-6)

  for (int kt = 0; kt < 8; ++kt) {
    const int cur = kt & 1;
    // wait for S(kt) only; S(kt+1) stays in flight (counted vmcnt, T4)
    if (kt < 7) asm volatile("s_waitcnt vmcnt(8)" ::: "memory");
    else        asm volatile("s_waitcnt vmcnt(0)" ::: "memory");
    __builtin_amdgcn_s_barrier();

    const char* Ab = (const char*)&As[cur][0];
    const char* Bb = (const char*)&Bs[cur][0];
    #pragma unroll
    for (int kk = 0; kk < 2; ++kk) {
      const int kb = kk * 64 + g * 16;           // k byte-offset within row
      bf16x8 bfrag[4];
      #pragma unroll
      for (int n = 0; n < 4; ++n)
        bfrag[n] = *(const bf16x8*)(Bb + (((wc * 64 + n * 16 + r0) * 128 + kb) ^ sw));
      #pragma unroll
      for (int m = 0; m < 4; ++m) {
        bf16x8 afrag = *(const bf16x8*)(Ab + (((wr * 64 + m * 16 + r0) * 128 + kb) ^ sw));
        #pragma unroll
        for (int n = 0; n < 4; ++n)
          acc[m][n] = __builtin_amdgcn_mfma_f32_16x16x32_bf16(afrag, bfrag[n],
                                                              acc[m][n], 0, 0, 0);
      }
    }
    // all LDS reads of buf[cur] done in this wave, then sync all waves,
    // then buf[cur] is free to be overwritten by S(kt+2).
    asm volatile("s_waitcnt lgkmcnt(0)" ::: "memory");
    __builtin_amdgcn_sched_barrier(0);
    __builtin_amdgcn_s_barrier();
    if (kt < 6) stage(cur, (kt + 2) * 64);
  }

  // ---- epilogue: exp(10*g); row sums + col sums (symmetry); pair dots ----
  float cs[4] = {0.f, 0.f, 0.f, 0.f};
  const int grow0 = brow + wr * 64;
  const int gcol0 = bcol + wc * 64;
  #pragma unroll
  for (int m = 0; m < 4; ++m) {
    #pragma unroll
    for (int j = 0; j < 4; ++j) {
      const int grow = grow0 + m * 16 + g * 4 + j;
      float v = 0.f;
      #pragma unroll
      for (int n = 0; n < 4; ++n) {
        const int gcol = gcol0 + n * 16 + r0;
        const float raw = acc[m][n][j];
        const float e = __expf(raw * TEMP_INV);
        if (grow != gcol) { v += e; cs[n] += e; }   // skip self-similarity
        if (pair && (grow + NPER == gcol)) {        // positive-pair raw dot
          s[grow] = raw;                            // dot(z_i, z_{i+NPER})
          s[gcol] = raw;                            // symmetric partner
        }
      }
      v += __shfl_xor(v, 1);
      v += __shfl_xor(v, 2);
      v += __shfl_xor(v, 4);
      v += __shfl_xor(v, 8);
      if (r0 == 0) racc[wc][wr * 64 + m * 16 + g * 4 + j] = v;
    }
  }
  #pragma unroll
  for (int n = 0; n < 4; ++n) {
    float v = cs[n];
    v += __shfl_xor(v, 16);
    v += __shfl_xor(v, 32);
    if (lane < 16) cacc[wr][wc * 64 + n * 16 + lane] = v;
  }
  __syncthreads();
  if (tid < 128) {
    atomicAdd(&rowsum[brow + tid], racc[0][tid] + racc[1][tid]);
  } else if (!diag) {
    const int i = tid - 128;
    atomicAdd(&rowsum[bcol + i], cacc[0][i] + cacc[1][i]);
  }
}

// ---------------------------------------------------------------------------
// Kernel 3: loss = mean_i( log(denom_i) - s_i/T )
// ---------------------------------------------------------------------------
__global__ __launch_bounds__(256) void k_loss(const float* __restrict__ rowsum,
                                              const float* __restrict__ s,
                                              float* __restrict__ out) {
  __shared__ float red[256];
  float acc = 0.f;
  for (int i = threadIdx.x; i < NROWS; i += 256)
    acc += logf(rowsum[i]) - s[i] * TEMP_INV;
  red[threadIdx.x] = acc;
  __syncthreads();
  for (int st = 128; st > 0; st >>= 1) {
    if (threadIdx.x < st) red[threadIdx.x] += red[threadIdx.x + st];
    __syncthreads();
  }
  if (threadIdx.x == 0) out[0] = red[0] / (float)NROWS;
}

extern "C" void kernel_launch(void* const* d_in, const int* in_sizes, int n_in,
                              void* d_out, int out_size, void* d_ws, size_t ws_size,
                              hipStream_t stream) {
  const float* v0 = (const float*)d_in[0];
  const float* v1 = (const float*)d_in[1];
  float* out = (float*)d_out;

  unsigned short* z = (unsigned short*)d_ws;                    // 8192*512*2 B
  float* rowsum = (float*)((char*)d_ws + (size_t)NROWS * DIM * 2);
  float* s      = rowsum + NROWS;

  k_normalize<<<NROWS / 4, 256, 0, stream>>>(v0, v1, z, rowsum);
  k_gemm_sym<<<NBLK, 256, 0, stream>>>(z, rowsum, s);
  k_loss<<<1, 256, 0, stream>>>(rowsum, s, out);
}